// Round 5
// baseline (828.228 us; speedup 1.0000x reference)
//
#include <hip/hip_runtime.h>

#define ENTITIES_N 100000
#define RELATIONS_N 1000
#define WIDTH (2 * ENTITIES_N + RELATIONS_N)   // 201000 floats per row
#define QWIDTH (WIDTH / 4)                     // 50250 float4 per row
#define STORES 8                               // float4 stores per thread
#define Q_PER_BLOCK (256 * STORES)             // 2048 float4 = 32 KB per block

typedef float vfloat4 __attribute__((ext_vector_type(4)));

// Fused one-hot materialization, deep-ILP variant: 8 nontemporal dwordx4
// stores per thread. Store j of a block covers a contiguous 4 KB span
// (lane i at 16B*i), so every 64 B line is produced whole by one instruction.
// Row r has 1.0 at columns hID[r], E+rID[r], E+R+tID[r]; segment boundaries
// are multiples of 4 so each aligned float4 window matches at most one target.
__global__ __launch_bounds__(256) void onehot_rows(
        const int* __restrict__ hID,
        const int* __restrict__ rID,
        const int* __restrict__ tID,
        vfloat4* __restrict__ out) {
    const int row = blockIdx.y;

    // Block-uniform index loads (12 KB total across all rows -> L2-hot).
    const int h = hID[row];
    const int r = ENTITIES_N + rID[row];
    const int t = ENTITIES_N + RELATIONS_N + tID[row];

    vfloat4* rowOut = out + (long long)row * QWIDTH;
    const int qBase = blockIdx.x * Q_PER_BLOCK + threadIdx.x;

#pragma unroll
    for (int j = 0; j < STORES; ++j) {
        const int q = qBase + j * 256;
        if (q < QWIDTH) {
            const int col = q * 4;
            vfloat4 v;
            v.x = (col     == h || col     == r || col     == t) ? 1.0f : 0.0f;
            v.y = (col + 1 == h || col + 1 == r || col + 1 == t) ? 1.0f : 0.0f;
            v.z = (col + 2 == h || col + 2 == r || col + 2 == t) ? 1.0f : 0.0f;
            v.w = (col + 3 == h || col + 3 == r || col + 3 == t) ? 1.0f : 0.0f;
            __builtin_nontemporal_store(v, &rowOut[q]);
        }
    }
}

extern "C" void kernel_launch(void* const* d_in, const int* in_sizes, int n_in,
                              void* d_out, int out_size, void* d_ws, size_t ws_size,
                              hipStream_t stream) {
    // Inputs (setup_inputs order): z [B,128] f32 (unused), hID [B] i32, rID [B] i32, tID [B] i32
    const int* hID = (const int*)d_in[1];
    const int* rID = (const int*)d_in[2];
    const int* tID = (const int*)d_in[3];
    vfloat4* out = (vfloat4*)d_out;

    const int batch = in_sizes[2];

    dim3 grid((QWIDTH + Q_PER_BLOCK - 1) / Q_PER_BLOCK, batch);  // (25, 1024)
    onehot_rows<<<grid, 256, 0, stream>>>(hID, rID, tID, out);
}

// Round 6
// 776.998 us; speedup vs baseline: 1.0659x; 1.0659x over previous
//
#include <hip/hip_runtime.h>

#define ENTITIES_N 100000
#define RELATIONS_N 1000
#define WIDTH (2 * ENTITIES_N + RELATIONS_N)   // 201000

// Structure (best measured, R1): graph memset node (SDMA, ~3.3 TB/s — beats
// compute-shader streaming stores which plateau at ~2.8 TB/s across nt/plain/
// ILP variants, R3-R5) zeroes the 823 MB output, then a tiny scatter kernel
// writes the 3*1024 ones. h/r/t column segments are disjoint -> no conflicts.
__global__ void scatter_ones_i32(const int* __restrict__ hID,
                                 const int* __restrict__ rID,
                                 const int* __restrict__ tID,
                                 float* __restrict__ out, int batch) {
    int row = blockIdx.x * blockDim.x + threadIdx.x;
    if (row >= batch) return;
    long long base = (long long)row * WIDTH;
    out[base + (long long)hID[row]] = 1.0f;
    out[base + ENTITIES_N + (long long)rID[row]] = 1.0f;
    out[base + ENTITIES_N + RELATIONS_N + (long long)tID[row]] = 1.0f;
}

__global__ void scatter_ones_i64(const long long* __restrict__ hID,
                                 const int* __restrict__ rID,
                                 const int* __restrict__ tID,
                                 float* __restrict__ out, int batch) {
    int row = blockIdx.x * blockDim.x + threadIdx.x;
    if (row >= batch) return;
    long long base = (long long)row * WIDTH;
    out[base + hID[row]] = 1.0f;
    out[base + ENTITIES_N + (long long)rID[row]] = 1.0f;
    out[base + ENTITIES_N + RELATIONS_N + (long long)tID[row]] = 1.0f;
}

extern "C" void kernel_launch(void* const* d_in, const int* in_sizes, int n_in,
                              void* d_out, int out_size, void* d_ws, size_t ws_size,
                              hipStream_t stream) {
    // Inputs (setup_inputs order): z [B,128] f32 (unused), hID [B] int, rID [B] i32, tID [B] i32
    const int* rID = (const int*)d_in[2];
    const int* tID = (const int*)d_in[3];
    float* out = (float*)d_out;

    const int batch = in_sizes[2];  // rID is definitely int32, one elem per row

    // Zero the whole output. As a captured memset node this takes the SDMA
    // path (~250 us for 823 MB) — faster than any compute-store variant tried.
    hipMemsetAsync(d_out, 0, (size_t)out_size * sizeof(float), stream);

    const int block = 256;
    const int grid = (batch + block - 1) / block;
    if (in_sizes[1] == batch) {
        scatter_ones_i32<<<grid, block, 0, stream>>>((const int*)d_in[1], rID, tID, out, batch);
    } else {
        scatter_ones_i64<<<grid, block, 0, stream>>>((const long long*)d_in[1], rID, tID, out, batch);
    }
}